// Round 2
// baseline (425.836 us; speedup 1.0000x reference)
//
#include <hip/hip_runtime.h>

namespace {

struct SelState {
    unsigned k[3];     // rank to find at each pass (1-based)
    unsigned sel[3];   // sel[0]=top 12 bits, sel[1]=top 24 bits, sel[2]=full key
    float threshold;
};

constexpr int BINS12 = 4096;
constexpr int BINS8  = 256;

// Monotone map: float bits -> unsigned, ascending with float value.
__device__ __forceinline__ unsigned f2key(float f) {
    unsigned u = __float_as_uint(f);
    return (u & 0x80000000u) ? ~u : (u | 0x80000000u);
}
__device__ __forceinline__ float key2f(unsigned k) {
    return __uint_as_float((k & 0x80000000u) ? (k & 0x7fffffffu) : ~k);
}

__global__ void init_kernel(unsigned* __restrict__ hist0, unsigned* __restrict__ hist1,
                            unsigned* __restrict__ hist2, SelState* __restrict__ st,
                            unsigned total_k) {
    int t = blockIdx.x * blockDim.x + threadIdx.x;
    int stride = gridDim.x * blockDim.x;
    for (int i = t; i < BINS12; i += stride) { hist0[i] = 0; hist1[i] = 0; }
    if (t < BINS8) hist2[t] = 0;
    if (t == 0) {
        st->k[0] = total_k; st->k[1] = 0; st->k[2] = 0;
        st->sel[0] = 0; st->sel[1] = 0; st->sel[2] = 0;
        st->threshold = 0.f;
    }
}

template <int PASS>
__global__ __launch_bounds__(256) void hist_kernel(const float* __restrict__ x, long long n,
                                                   unsigned* __restrict__ hist,
                                                   const SelState* __restrict__ st) {
    constexpr int BINS = (PASS == 2) ? BINS8 : BINS12;
    __shared__ unsigned lh[BINS];
    for (int i = threadIdx.x; i < BINS; i += 256) lh[i] = 0;
    __syncthreads();

    unsigned sel = 0;
    if (PASS == 1) sel = st->sel[0];
    if (PASS == 2) sel = st->sel[1];

    long long n4 = n >> 2;
    long long tid = (long long)blockIdx.x * blockDim.x + threadIdx.x;
    long long stride = (long long)gridDim.x * blockDim.x;
    const float4* x4 = (const float4*)x;

    for (long long i = tid; i < n4; i += stride) {
        float4 v = x4[i];
        float vv[4] = {v.x, v.y, v.z, v.w};
#pragma unroll
        for (int c = 0; c < 4; ++c) {
            unsigned key = f2key(vv[c]);
            if (PASS == 0) {
                atomicAdd(&lh[key >> 20], 1u);
            } else if (PASS == 1) {
                if ((key >> 20) == sel) atomicAdd(&lh[(key >> 8) & 0xFFFu], 1u);
            } else {
                if ((key >> 8) == sel) atomicAdd(&lh[key & 0xFFu], 1u);
            }
        }
    }
    // tail (n may not be divisible by 4)
    for (long long i = (n4 << 2) + tid; i < n; i += stride) {
        unsigned key = f2key(x[i]);
        if (PASS == 0) {
            atomicAdd(&lh[key >> 20], 1u);
        } else if (PASS == 1) {
            if ((key >> 20) == sel) atomicAdd(&lh[(key >> 8) & 0xFFFu], 1u);
        } else {
            if ((key >> 8) == sel) atomicAdd(&lh[key & 0xFFu], 1u);
        }
    }

    __syncthreads();
    for (int i = threadIdx.x; i < BINS; i += 256) {
        unsigned c = lh[i];
        if (c) atomicAdd(&hist[i], c);
    }
}

// Find the bin (descending) containing the k-th largest; update state.
template <int PASS>
__global__ void scan_kernel(const unsigned* __restrict__ hist, SelState* __restrict__ st) {
    constexpr int NB = (PASS == 2) ? BINS8 : BINS12;
    constexpr int CH = NB / 256;  // bins per thread, in descending order
    __shared__ unsigned counts[NB];  // counts in DESCENDING bin order
    __shared__ unsigned csum[256];
    int t = threadIdx.x;
    unsigned s = 0;
#pragma unroll
    for (int j = 0; j < CH; ++j) {
        int oidx = t * CH + j;
        unsigned c = hist[NB - 1 - oidx];
        counts[oidx] = c;
        s += c;
    }
    csum[t] = s;
    __syncthreads();
    if (t == 0) {
        unsigned k = st->k[PASS];
        unsigned cum = 0;
        int cidx = 0;
        while (cidx < 255 && cum + csum[cidx] < k) { cum += csum[cidx]; ++cidx; }
        int sel_bin = 0;
        unsigned krem = k;
        for (int j = cidx * CH; j < NB; ++j) {
            unsigned cnt = counts[j];
            if (cum + cnt >= k) { sel_bin = NB - 1 - j; krem = k - cum; break; }
            cum += cnt;
        }
        if (PASS == 0) {
            st->sel[0] = (unsigned)sel_bin;
            st->k[1] = krem;
        } else if (PASS == 1) {
            st->sel[1] = (st->sel[0] << 12) | (unsigned)sel_bin;
            st->k[2] = krem;
        } else {
            unsigned key = (st->sel[1] << 8) | (unsigned)sel_bin;
            st->sel[2] = key;
            st->threshold = key2f(key);
        }
    }
}

__global__ __launch_bounds__(256) void gate_kernel(const float* __restrict__ x,
                                                   float* __restrict__ out, long long n,
                                                   const SelState* __restrict__ st) {
    float thr = st->threshold;
    long long n4 = n >> 2;
    long long tid = (long long)blockIdx.x * blockDim.x + threadIdx.x;
    long long stride = (long long)gridDim.x * blockDim.x;
    const float4* x4 = (const float4*)x;
    float4* o4 = (float4*)out;
    for (long long i = tid; i < n4; i += stride) {
        float4 v = x4[i];
        float4 r;
        r.x = (v.x >= thr) ? fmaxf(v.x, 0.f) : 0.f;
        r.y = (v.y >= thr) ? fmaxf(v.y, 0.f) : 0.f;
        r.z = (v.z >= thr) ? fmaxf(v.z, 0.f) : 0.f;
        r.w = (v.w >= thr) ? fmaxf(v.w, 0.f) : 0.f;
        o4[i] = r;
    }
    for (long long i = (n4 << 2) + tid; i < n; i += stride) {
        float v = x[i];
        out[i] = (v >= thr) ? fmaxf(v, 0.f) : 0.f;
    }
}

}  // namespace

extern "C" void kernel_launch(void* const* d_in, const int* in_sizes, int n_in,
                              void* d_out, int out_size, void* d_ws, size_t ws_size,
                              hipStream_t stream) {
    const float* x = (const float*)d_in[0];
    float* out = (float*)d_out;
    long long n = (long long)in_sizes[0];

    // Reference: K=64 per sample, batch=4096 rows -> total_k = min(64*4096, n)
    long long tk = 64LL * 4096LL;
    if (tk > n) tk = n;
    unsigned total_k = (unsigned)tk;

    char* ws = (char*)d_ws;
    unsigned* hist0 = (unsigned*)(ws);            // 4096 * 4 = 16 KiB
    unsigned* hist1 = (unsigned*)(ws + 16384);    // 4096 * 4 = 16 KiB
    unsigned* hist2 = (unsigned*)(ws + 32768);    // 256 * 4  = 1 KiB
    SelState* st    = (SelState*)(ws + 33792);

    const int blocks = 2048;

    init_kernel<<<8, 1024, 0, stream>>>(hist0, hist1, hist2, st, total_k);
    hist_kernel<0><<<blocks, 256, 0, stream>>>(x, n, hist0, st);
    scan_kernel<0><<<1, 256, 0, stream>>>(hist0, st);
    hist_kernel<1><<<blocks, 256, 0, stream>>>(x, n, hist1, st);
    scan_kernel<1><<<1, 256, 0, stream>>>(hist1, st);
    hist_kernel<2><<<blocks, 256, 0, stream>>>(x, n, hist2, st);
    scan_kernel<2><<<1, 256, 0, stream>>>(hist2, st);
    gate_kernel<<<blocks, 256, 0, stream>>>(x, out, n, st);
}

// Round 3
// 307.902 us; speedup vs baseline: 1.3830x; 1.3830x over previous
//
#include <hip/hip_runtime.h>

namespace {

struct SelState {
    unsigned k[3];     // rank to find at each pass (1-based)
    unsigned sel[3];   // sel[0]=top 12 bits, sel[1]=top 24 bits, sel[2]=full key
    float threshold;
    unsigned flag;     // 0 = compact path, 1 = fallback (full re-read), 2 = undecided
    unsigned bufcount; // number of compacted candidates
    unsigned overflow; // any block/buffer overflow -> fallback
};

constexpr int BINS12 = 4096;
constexpr int BINS8  = 256;
constexpr int LCAP   = 4096;            // per-block LDS staging capacity (16 KiB)
constexpr float GUESS = 2.5f;           // speculative lower bound on threshold

// Monotone map: float bits -> unsigned, ascending with float value.
__device__ __forceinline__ unsigned f2key(float f) {
    unsigned u = __float_as_uint(f);
    return (u & 0x80000000u) ? ~u : (u | 0x80000000u);
}
__device__ __forceinline__ float key2f(unsigned k) {
    return __uint_as_float((k & 0x80000000u) ? (k & 0x7fffffffu) : ~k);
}

__global__ void init_kernel(unsigned* __restrict__ hist0, unsigned* __restrict__ hist1,
                            unsigned* __restrict__ hist2, SelState* __restrict__ st,
                            unsigned total_k, unsigned force_fb) {
    int t = blockIdx.x * blockDim.x + threadIdx.x;
    int stride = gridDim.x * blockDim.x;
    for (int i = t; i < BINS12; i += stride) { hist0[i] = 0; hist1[i] = 0; }
    if (t < BINS8) hist2[t] = 0;
    if (t == 0) {
        st->k[0] = total_k; st->k[1] = 0; st->k[2] = 0;
        st->sel[0] = 0; st->sel[1] = 0; st->sel[2] = 0;
        st->threshold = 0.f;
        st->flag = force_fb ? 1u : 2u;
        st->bufcount = 0;
        st->overflow = 0;
    }
}

// Single streaming read: compact all keys >= GKEY into buf via per-block LDS staging.
__global__ __launch_bounds__(256) void pass1_kernel(const float* __restrict__ x, long long n,
                                                    unsigned* __restrict__ buf, unsigned bufcap,
                                                    SelState* __restrict__ st) {
    if (st->flag != 2u) return;  // forced fallback
    __shared__ unsigned lcand[LCAP];
    __shared__ unsigned lcnt;
    __shared__ unsigned gbase;
    if (threadIdx.x == 0) lcnt = 0;
    __syncthreads();

    const unsigned GKEY = f2key(GUESS);
    long long n4 = n >> 2;
    long long tid = (long long)blockIdx.x * blockDim.x + threadIdx.x;
    long long stride = (long long)gridDim.x * blockDim.x;
    const float4* x4 = (const float4*)x;

    for (long long i = tid; i < n4; i += stride) {
        float4 v = x4[i];
        float vv[4] = {v.x, v.y, v.z, v.w};
#pragma unroll
        for (int c = 0; c < 4; ++c) {
            unsigned key = f2key(vv[c]);
            if (key >= GKEY) {
                unsigned idx = atomicAdd(&lcnt, 1u);
                if (idx < LCAP) lcand[idx] = key;
            }
        }
    }
    for (long long i = (n4 << 2) + tid; i < n; i += stride) {
        unsigned key = f2key(x[i]);
        if (key >= GKEY) {
            unsigned idx = atomicAdd(&lcnt, 1u);
            if (idx < LCAP) lcand[idx] = key;
        }
    }

    __syncthreads();
    unsigned cnt = lcnt;
    if (cnt > LCAP) cnt = LCAP;
    if (threadIdx.x == 0) {
        if (lcnt > LCAP) atomicOr(&st->overflow, 1u);
        unsigned base = atomicAdd(&st->bufcount, cnt);
        if (base + cnt > bufcap) atomicOr(&st->overflow, 1u);
        gbase = base;
    }
    __syncthreads();
    unsigned base = gbase;
    for (unsigned i = threadIdx.x; i < cnt; i += 256) {
        unsigned dst = base + i;
        if (dst < bufcap) buf[dst] = lcand[i];
    }
}

__global__ void decide_kernel(SelState* __restrict__ st, unsigned total_k) {
    if (st->flag == 2u)
        st->flag = (st->overflow || st->bufcount < total_k) ? 1u : 0u;
}

// Dual-mode histogram: compact path reads keys from buf; fallback reads full x.
template <int PASS>
__global__ __launch_bounds__(256) void hist_dual(const float* __restrict__ x, long long n,
                                                 const unsigned* __restrict__ buf,
                                                 unsigned* __restrict__ hist,
                                                 const SelState* __restrict__ st) {
    constexpr int BINS = (PASS == 2) ? BINS8 : BINS12;
    __shared__ unsigned lh[BINS];
    for (int i = threadIdx.x; i < BINS; i += 256) lh[i] = 0;
    __syncthreads();

    const bool fb = (st->flag == 1u);
    unsigned sel = 0;
    if (PASS == 1) sel = st->sel[0];
    if (PASS == 2) sel = st->sel[1];

    long long tid = (long long)blockIdx.x * blockDim.x + threadIdx.x;
    long long stride = (long long)gridDim.x * blockDim.x;

    if (fb) {
        long long n4 = n >> 2;
        const float4* x4 = (const float4*)x;
        for (long long i = tid; i < n4; i += stride) {
            float4 v = x4[i];
            float vv[4] = {v.x, v.y, v.z, v.w};
#pragma unroll
            for (int c = 0; c < 4; ++c) {
                unsigned key = f2key(vv[c]);
                if (PASS == 0) atomicAdd(&lh[key >> 20], 1u);
                else if (PASS == 1) { if ((key >> 20) == sel) atomicAdd(&lh[(key >> 8) & 0xFFFu], 1u); }
                else { if ((key >> 8) == sel) atomicAdd(&lh[key & 0xFFu], 1u); }
            }
        }
        for (long long i = (n4 << 2) + tid; i < n; i += stride) {
            unsigned key = f2key(x[i]);
            if (PASS == 0) atomicAdd(&lh[key >> 20], 1u);
            else if (PASS == 1) { if ((key >> 20) == sel) atomicAdd(&lh[(key >> 8) & 0xFFFu], 1u); }
            else { if ((key >> 8) == sel) atomicAdd(&lh[key & 0xFFu], 1u); }
        }
    } else {
        long long cnt = (long long)st->bufcount;
        long long c4 = cnt >> 2;
        const uint4* b4 = (const uint4*)buf;
        for (long long i = tid; i < c4; i += stride) {
            uint4 kv = b4[i];
            unsigned kk[4] = {kv.x, kv.y, kv.z, kv.w};
#pragma unroll
            for (int c = 0; c < 4; ++c) {
                unsigned key = kk[c];
                if (PASS == 0) atomicAdd(&lh[key >> 20], 1u);
                else if (PASS == 1) { if ((key >> 20) == sel) atomicAdd(&lh[(key >> 8) & 0xFFFu], 1u); }
                else { if ((key >> 8) == sel) atomicAdd(&lh[key & 0xFFu], 1u); }
            }
        }
        for (long long i = (c4 << 2) + tid; i < cnt; i += stride) {
            unsigned key = buf[i];
            if (PASS == 0) atomicAdd(&lh[key >> 20], 1u);
            else if (PASS == 1) { if ((key >> 20) == sel) atomicAdd(&lh[(key >> 8) & 0xFFFu], 1u); }
            else { if ((key >> 8) == sel) atomicAdd(&lh[key & 0xFFu], 1u); }
        }
    }

    __syncthreads();
    for (int i = threadIdx.x; i < BINS; i += 256) {
        unsigned c = lh[i];
        if (c) atomicAdd(&hist[i], c);
    }
}

// Find the bin (descending) containing the k-th largest; update state. Path-agnostic.
template <int PASS>
__global__ void scan_kernel(const unsigned* __restrict__ hist, SelState* __restrict__ st) {
    constexpr int NB = (PASS == 2) ? BINS8 : BINS12;
    constexpr int CH = NB / 256;
    __shared__ unsigned counts[NB];  // counts in DESCENDING bin order
    __shared__ unsigned csum[256];
    int t = threadIdx.x;
    unsigned s = 0;
#pragma unroll
    for (int j = 0; j < CH; ++j) {
        int oidx = t * CH + j;
        unsigned c = hist[NB - 1 - oidx];
        counts[oidx] = c;
        s += c;
    }
    csum[t] = s;
    __syncthreads();
    if (t == 0) {
        unsigned k = st->k[PASS];
        unsigned cum = 0;
        int cidx = 0;
        while (cidx < 255 && cum + csum[cidx] < k) { cum += csum[cidx]; ++cidx; }
        int sel_bin = 0;
        unsigned krem = k;
        for (int j = cidx * CH; j < NB; ++j) {
            unsigned cnt = counts[j];
            if (cum + cnt >= k) { sel_bin = NB - 1 - j; krem = k - cum; break; }
            cum += cnt;
        }
        if (PASS == 0) {
            st->sel[0] = (unsigned)sel_bin;
            st->k[1] = krem;
        } else if (PASS == 1) {
            st->sel[1] = (st->sel[0] << 12) | (unsigned)sel_bin;
            st->k[2] = krem;
        } else {
            unsigned key = (st->sel[1] << 8) | (unsigned)sel_bin;
            st->sel[2] = key;
            st->threshold = key2f(key);
        }
    }
}

__global__ __launch_bounds__(256) void gate_kernel(const float* __restrict__ x,
                                                   float* __restrict__ out, long long n,
                                                   const SelState* __restrict__ st) {
    float thr = st->threshold;
    long long n4 = n >> 2;
    long long tid = (long long)blockIdx.x * blockDim.x + threadIdx.x;
    long long stride = (long long)gridDim.x * blockDim.x;
    const float4* x4 = (const float4*)x;
    float4* o4 = (float4*)out;
    for (long long i = tid; i < n4; i += stride) {
        float4 v = x4[i];
        float4 r;
        r.x = (v.x >= thr) ? fmaxf(v.x, 0.f) : 0.f;
        r.y = (v.y >= thr) ? fmaxf(v.y, 0.f) : 0.f;
        r.z = (v.z >= thr) ? fmaxf(v.z, 0.f) : 0.f;
        r.w = (v.w >= thr) ? fmaxf(v.w, 0.f) : 0.f;
        o4[i] = r;
    }
    for (long long i = (n4 << 2) + tid; i < n; i += stride) {
        float v = x[i];
        out[i] = (v >= thr) ? fmaxf(v, 0.f) : 0.f;
    }
}

}  // namespace

extern "C" void kernel_launch(void* const* d_in, const int* in_sizes, int n_in,
                              void* d_out, int out_size, void* d_ws, size_t ws_size,
                              hipStream_t stream) {
    const float* x = (const float*)d_in[0];
    float* out = (float*)d_out;
    long long n = (long long)in_sizes[0];

    long long tk = 64LL * 4096LL;
    if (tk > n) tk = n;
    unsigned total_k = (unsigned)tk;

    char* ws = (char*)d_ws;
    unsigned* hist0 = (unsigned*)(ws);            // 4096 * 4 = 16 KiB
    unsigned* hist1 = (unsigned*)(ws + 16384);    // 4096 * 4 = 16 KiB
    unsigned* hist2 = (unsigned*)(ws + 32768);    // 256 * 4  = 1 KiB
    SelState* st    = (SelState*)(ws + 33792);
    unsigned* buf   = (unsigned*)(ws + 65536);    // candidate keys

    // Candidate buffer capacity from remaining ws (cap at 8M entries = 32 MiB).
    unsigned bufcap = 0;
    if (ws_size > 65536) {
        size_t avail = (ws_size - 65536) / 4;
        bufcap = (unsigned)((avail > 8u * 1024u * 1024u) ? 8u * 1024u * 1024u : avail);
    }
    // Need comfortable headroom above total_k for the compact path to be usable.
    unsigned force_fb = (bufcap < 2u * total_k) ? 1u : 0u;

    const int blocks = 2048;

    init_kernel<<<8, 1024, 0, stream>>>(hist0, hist1, hist2, st, total_k, force_fb);
    pass1_kernel<<<blocks, 256, 0, stream>>>(x, n, buf, bufcap, st);
    decide_kernel<<<1, 1, 0, stream>>>(st, total_k);
    hist_dual<0><<<blocks, 256, 0, stream>>>(x, n, buf, hist0, st);
    scan_kernel<0><<<1, 256, 0, stream>>>(hist0, st);
    hist_dual<1><<<blocks, 256, 0, stream>>>(x, n, buf, hist1, st);
    scan_kernel<1><<<1, 256, 0, stream>>>(hist1, st);
    hist_dual<2><<<blocks, 256, 0, stream>>>(x, n, buf, hist2, st);
    scan_kernel<2><<<1, 256, 0, stream>>>(hist2, st);
    gate_kernel<<<blocks, 256, 0, stream>>>(x, out, n, st);
}

// Round 5
// 256.025 us; speedup vs baseline: 1.6633x; 1.2026x over previous
//
#include <hip/hip_runtime.h>

namespace {

struct SelState {
    unsigned k[3];      // rank to find at each pass (1-based)
    unsigned sel[3];    // sel[0]=top12, sel[1]=top24, sel[2]=full 32-bit key of threshold
    unsigned forced_fb; // host decided ws too small -> always fallback
    unsigned bufcount;  // number of compacted candidates
    unsigned overflow;  // LDS or buffer overflow -> fallback
};

constexpr int BINS12 = 4096;
constexpr int BINS8  = 256;
constexpr int LCAP   = 2048;   // per-block candidate staging (2 x 8 KiB LDS)
constexpr float GUESS = 2.5f;  // speculative lower bound on threshold (P(N>2.5)=6.2e-3)

// Monotone map: float bits -> unsigned, ascending with float value.
__device__ __forceinline__ unsigned f2key(float f) {
    unsigned u = __float_as_uint(f);
    return (u & 0x80000000u) ? ~u : (u | 0x80000000u);
}
__device__ __forceinline__ float key2f(unsigned k) {
    return __uint_as_float((k & 0x80000000u) ? (k & 0x7fffffffu) : ~k);
}
__device__ __forceinline__ bool is_fb(const SelState* st, unsigned total_k) {
    return st->forced_fb || st->overflow || (st->bufcount < total_k);
}

__global__ void init_kernel(unsigned* __restrict__ hist0, unsigned* __restrict__ hist1,
                            unsigned* __restrict__ hist2, SelState* __restrict__ st,
                            unsigned total_k, unsigned force_fb) {
    int t = blockIdx.x * blockDim.x + threadIdx.x;
    int stride = gridDim.x * blockDim.x;
    for (int i = t; i < BINS12; i += stride) { hist0[i] = 0; hist1[i] = 0; }
    if (t < BINS8) hist2[t] = 0;
    if (t == 0) {
        st->k[0] = total_k; st->k[1] = 0; st->k[2] = 0;
        st->sel[0] = 0; st->sel[1] = 0; st->sel[2] = 0;
        st->forced_fb = force_fb;
        st->bufcount = 0;
        st->overflow = 0;
    }
}

// Fused: stream x once -> write out=0 everywhere, compact (key,idx) of candidates >= GUESS.
__global__ __launch_bounds__(256) void pass1_kernel(const float* __restrict__ x,
                                                    float* __restrict__ out, long long n,
                                                    unsigned* __restrict__ keys,
                                                    unsigned* __restrict__ idxs,
                                                    unsigned bufcap, SelState* __restrict__ st) {
    if (st->forced_fb) return;  // fallback path rewrites everything later
    __shared__ unsigned lkey[LCAP];
    __shared__ unsigned lidx[LCAP];
    __shared__ unsigned lcnt;
    __shared__ unsigned gbase;
    if (threadIdx.x == 0) lcnt = 0;
    __syncthreads();

    const unsigned GKEY = f2key(GUESS);
    long long n4 = n >> 2;
    long long tid = (long long)blockIdx.x * blockDim.x + threadIdx.x;
    long long stride = (long long)gridDim.x * blockDim.x;
    const float4* x4 = (const float4*)x;
    float4* o4 = (float4*)out;
    const float4 z4 = make_float4(0.f, 0.f, 0.f, 0.f);

    for (long long i = tid; i < n4; i += stride) {
        float4 v = x4[i];
        o4[i] = z4;
        float vv[4] = {v.x, v.y, v.z, v.w};
#pragma unroll
        for (int c = 0; c < 4; ++c) {
            unsigned key = f2key(vv[c]);
            if (key >= GKEY) {
                unsigned p = atomicAdd(&lcnt, 1u);
                if (p < LCAP) { lkey[p] = key; lidx[p] = (unsigned)((i << 2) + c); }
            }
        }
    }
    for (long long i = (n4 << 2) + tid; i < n; i += stride) {
        float v = x[i];
        out[i] = 0.f;
        unsigned key = f2key(v);
        if (key >= GKEY) {
            unsigned p = atomicAdd(&lcnt, 1u);
            if (p < LCAP) { lkey[p] = key; lidx[p] = (unsigned)i; }
        }
    }

    __syncthreads();
    unsigned cnt = lcnt;
    if (cnt > LCAP) cnt = LCAP;
    if (threadIdx.x == 0) {
        if (lcnt > LCAP) atomicOr(&st->overflow, 1u);
        unsigned base = atomicAdd(&st->bufcount, cnt);
        if (base + cnt > bufcap) atomicOr(&st->overflow, 1u);
        gbase = base;
    }
    __syncthreads();
    unsigned base = gbase;
    for (unsigned i = threadIdx.x; i < cnt; i += 256) {
        unsigned dst = base + i;
        if (dst < bufcap) { keys[dst] = lkey[i]; idxs[dst] = lidx[i]; }
    }
}

// Dual-mode histogram: compact path reads candidate keys; fallback reads full x.
template <int PASS>
__global__ __launch_bounds__(256) void hist_dual(const float* __restrict__ x, long long n,
                                                 const unsigned* __restrict__ keys,
                                                 unsigned* __restrict__ hist,
                                                 const SelState* __restrict__ st,
                                                 unsigned total_k) {
    constexpr int BINS = (PASS == 2) ? BINS8 : BINS12;
    __shared__ unsigned lh[BINS];
    for (int i = threadIdx.x; i < BINS; i += 256) lh[i] = 0;
    __syncthreads();

    const bool fb = is_fb(st, total_k);
    unsigned sel = 0;
    if (PASS == 1) sel = st->sel[0];
    if (PASS == 2) sel = st->sel[1];

    long long tid = (long long)blockIdx.x * blockDim.x + threadIdx.x;
    long long stride = (long long)gridDim.x * blockDim.x;

    if (fb) {
        long long n4 = n >> 2;
        const float4* x4 = (const float4*)x;
        for (long long i = tid; i < n4; i += stride) {
            float4 v = x4[i];
            float vv[4] = {v.x, v.y, v.z, v.w};
#pragma unroll
            for (int c = 0; c < 4; ++c) {
                unsigned key = f2key(vv[c]);
                if (PASS == 0) atomicAdd(&lh[key >> 20], 1u);
                else if (PASS == 1) { if ((key >> 20) == sel) atomicAdd(&lh[(key >> 8) & 0xFFFu], 1u); }
                else { if ((key >> 8) == sel) atomicAdd(&lh[key & 0xFFu], 1u); }
            }
        }
        for (long long i = (n4 << 2) + tid; i < n; i += stride) {
            unsigned key = f2key(x[i]);
            if (PASS == 0) atomicAdd(&lh[key >> 20], 1u);
            else if (PASS == 1) { if ((key >> 20) == sel) atomicAdd(&lh[(key >> 8) & 0xFFFu], 1u); }
            else { if ((key >> 8) == sel) atomicAdd(&lh[key & 0xFFu], 1u); }
        }
    } else {
        long long cnt = (long long)st->bufcount;
        long long c4 = cnt >> 2;
        const uint4* k4 = (const uint4*)keys;
        for (long long i = tid; i < c4; i += stride) {
            uint4 kv = k4[i];
            unsigned kk[4] = {kv.x, kv.y, kv.z, kv.w};
#pragma unroll
            for (int c = 0; c < 4; ++c) {
                unsigned key = kk[c];
                if (PASS == 0) atomicAdd(&lh[key >> 20], 1u);
                else if (PASS == 1) { if ((key >> 20) == sel) atomicAdd(&lh[(key >> 8) & 0xFFFu], 1u); }
                else { if ((key >> 8) == sel) atomicAdd(&lh[key & 0xFFu], 1u); }
            }
        }
        for (long long i = (c4 << 2) + tid; i < cnt; i += stride) {
            unsigned key = keys[i];
            if (PASS == 0) atomicAdd(&lh[key >> 20], 1u);
            else if (PASS == 1) { if ((key >> 20) == sel) atomicAdd(&lh[(key >> 8) & 0xFFFu], 1u); }
            else { if ((key >> 8) == sel) atomicAdd(&lh[key & 0xFFu], 1u); }
        }
    }

    __syncthreads();
    for (int i = threadIdx.x; i < BINS; i += 256) {
        unsigned c = lh[i];
        if (c) atomicAdd(&hist[i], c);
    }
}

// Find the bin (descending) containing the k-th largest; update state. Path-agnostic.
template <int PASS>
__global__ void scan_kernel(const unsigned* __restrict__ hist, SelState* __restrict__ st) {
    constexpr int NB = (PASS == 2) ? BINS8 : BINS12;
    constexpr int CH = NB / 256;
    __shared__ unsigned counts[NB];  // counts in DESCENDING bin order
    __shared__ unsigned csum[256];
    int t = threadIdx.x;
    unsigned s = 0;
#pragma unroll
    for (int j = 0; j < CH; ++j) {
        int oidx = t * CH + j;
        unsigned c = hist[NB - 1 - oidx];
        counts[oidx] = c;
        s += c;
    }
    csum[t] = s;
    __syncthreads();
    if (t == 0) {
        unsigned k = st->k[PASS];
        unsigned cum = 0;
        int cidx = 0;
        while (cidx < 255 && cum + csum[cidx] < k) { cum += csum[cidx]; ++cidx; }
        int sel_bin = 0;
        unsigned krem = k;
        for (int j = cidx * CH; j < NB; ++j) {
            unsigned cnt = counts[j];
            if (cum + cnt >= k) { sel_bin = NB - 1 - j; krem = k - cum; break; }
            cum += cnt;
        }
        if (PASS == 0) {
            st->sel[0] = (unsigned)sel_bin;
            st->k[1] = krem;
        } else if (PASS == 1) {
            st->sel[1] = (st->sel[0] << 12) | (unsigned)sel_bin;
            st->k[2] = krem;
        } else {
            st->sel[2] = (st->sel[1] << 8) | (unsigned)sel_bin;
        }
    }
}

// Compact path: scatter candidate values >= threshold. Fallback: full gate over x.
__global__ __launch_bounds__(256) void gate_dual(const float* __restrict__ x,
                                                 float* __restrict__ out, long long n,
                                                 const unsigned* __restrict__ keys,
                                                 const unsigned* __restrict__ idxs,
                                                 const SelState* __restrict__ st,
                                                 unsigned total_k) {
    long long tid = (long long)blockIdx.x * blockDim.x + threadIdx.x;
    long long stride = (long long)gridDim.x * blockDim.x;
    if (is_fb(st, total_k)) {
        float thr = key2f(st->sel[2]);
        long long n4 = n >> 2;
        const float4* x4 = (const float4*)x;
        float4* o4 = (float4*)out;
        for (long long i = tid; i < n4; i += stride) {
            float4 v = x4[i];
            float4 r;
            r.x = (v.x >= thr) ? fmaxf(v.x, 0.f) : 0.f;
            r.y = (v.y >= thr) ? fmaxf(v.y, 0.f) : 0.f;
            r.z = (v.z >= thr) ? fmaxf(v.z, 0.f) : 0.f;
            r.w = (v.w >= thr) ? fmaxf(v.w, 0.f) : 0.f;
            o4[i] = r;
        }
        for (long long i = (n4 << 2) + tid; i < n; i += stride) {
            float v = x[i];
            out[i] = (v >= thr) ? fmaxf(v, 0.f) : 0.f;
        }
    } else {
        // All non-candidates already zeroed by pass1. thr >= GUESS > 0 so relu(x)=x here.
        unsigned tkey = st->sel[2];
        long long cnt = (long long)st->bufcount;
        for (long long i = tid; i < cnt; i += stride) {
            unsigned kk = keys[i];
            if (kk >= tkey) out[idxs[i]] = key2f(kk);
        }
    }
}

}  // namespace

extern "C" void kernel_launch(void* const* d_in, const int* in_sizes, int n_in,
                              void* d_out, int out_size, void* d_ws, size_t ws_size,
                              hipStream_t stream) {
    const float* x = (const float*)d_in[0];
    float* out = (float*)d_out;
    long long n = (long long)in_sizes[0];

    long long tk = 64LL * 4096LL;
    if (tk > n) tk = n;
    unsigned total_k = (unsigned)tk;

    char* ws = (char*)d_ws;
    unsigned* hist0 = (unsigned*)(ws);            // 16 KiB
    unsigned* hist1 = (unsigned*)(ws + 16384);    // 16 KiB
    unsigned* hist2 = (unsigned*)(ws + 32768);    // 1 KiB
    SelState* st    = (SelState*)(ws + 33792);

    // Candidate arrays: keys then idxs, each bufcap entries (bufcap multiple of 4).
    unsigned bufcap = 0;
    unsigned* keys = (unsigned*)(ws + 65536);
    unsigned* idxs = nullptr;
    if (ws_size > 65536) {
        size_t avail = (ws_size - 65536) / 8;  // two u32 arrays
        size_t cap = avail > 16u * 1024u * 1024u ? 16u * 1024u * 1024u : avail;
        bufcap = (unsigned)(cap & ~3ull);
        idxs = keys + bufcap;
    }
    unsigned force_fb = (bufcap < 2u * total_k || n > 0xFFFF0000LL) ? 1u : 0u;

    const int blocks = 2048;
    const int sblocks = 512;  // selection passes over small candidate buffer

    init_kernel<<<16, 256, 0, stream>>>(hist0, hist1, hist2, st, total_k, force_fb);
    pass1_kernel<<<blocks, 256, 0, stream>>>(x, out, n, keys, idxs, bufcap, st);
    hist_dual<0><<<sblocks, 256, 0, stream>>>(x, n, keys, hist0, st, total_k);
    scan_kernel<0><<<1, 256, 0, stream>>>(hist0, st);
    hist_dual<1><<<sblocks, 256, 0, stream>>>(x, n, keys, hist1, st, total_k);
    scan_kernel<1><<<1, 256, 0, stream>>>(hist1, st);
    hist_dual<2><<<sblocks, 256, 0, stream>>>(x, n, keys, hist2, st, total_k);
    scan_kernel<2><<<1, 256, 0, stream>>>(hist2, st);
    gate_dual<<<blocks, 256, 0, stream>>>(x, out, n, keys, idxs, st, total_k);
}

// Round 6
// 209.710 us; speedup vs baseline: 2.0306x; 1.2209x over previous
//
#include <hip/hip_runtime.h>

namespace {

struct SelState {
    unsigned forced_fb; // host decided ws too small -> always fallback
    unsigned bufcount;  // number of compacted candidates
    unsigned overflow;  // LDS or buffer overflow -> fallback
    unsigned sel0;      // top-12-bit bin of threshold (written by hist1_kernel blk0)
    unsigned k1;        // remaining rank within sel0 bin
    unsigned sel1;      // top-24 bits of threshold key (written by hist2_kernel blk0)
    unsigned k2;        // remaining rank within sel1 bin
};

constexpr int BINS12 = 4096;
constexpr int BINS8  = 256;
constexpr int LCAP   = 2048;   // per-block candidate staging (2 x 8 KiB LDS)
constexpr float GUESS = 2.5f;  // speculative lower bound; f2key(2.5) is a clean 12-bit bin boundary

using f4v = __attribute__((ext_vector_type(4))) float;

// Monotone map: float bits -> unsigned, ascending with float value.
__device__ __forceinline__ unsigned f2key(float f) {
    unsigned u = __float_as_uint(f);
    return (u & 0x80000000u) ? ~u : (u | 0x80000000u);
}
__device__ __forceinline__ float key2f(unsigned k) {
    return __uint_as_float((k & 0x80000000u) ? (k & 0x7fffffffu) : ~k);
}
__device__ __forceinline__ bool is_fb(const SelState* st, unsigned total_k) {
    return st->forced_fb || st->overflow || (st->bufcount < total_k);
}

// Per-block descending-rank scan of a finalized histogram. All blocks compute the
// same result (deterministic). res[0]=bin index, res[1]=remaining rank (1-based).
template <int NB>
__device__ __forceinline__ void scan_desc(const unsigned* __restrict__ hist, unsigned k,
                                          unsigned* __restrict__ lh, unsigned* __restrict__ res) {
    constexpr int CH = NB / 256;
    const int t = threadIdx.x;
    if (t == 0) { res[0] = 0; res[1] = k; }
    unsigned s = 0;
#pragma unroll
    for (int j = 0; j < CH; ++j) {
        unsigned c = hist[NB - 1 - (t * CH + j)];
        lh[t * CH + j] = c;  // descending bin order
        s += c;
    }
    __syncthreads();
    const int lane = t & 63, wid = t >> 6;
    unsigned v = s;
#pragma unroll
    for (int d = 1; d < 64; d <<= 1) {
        unsigned u = __shfl_up(v, (unsigned)d, 64);
        if (lane >= d) v += u;
    }
    __shared__ unsigned wp[4];
    if (lane == 63) wp[wid] = v;
    __syncthreads();
    unsigned add = 0;
    for (int w = 0; w < wid; ++w) add += wp[w];
    v += add;
    unsigned pre = v - s;  // exclusive prefix (descending-rank order)
    if (k > pre && k <= v) {  // exactly one thread (when total >= k)
        unsigned cum = pre;
#pragma unroll
        for (int j = 0; j < CH; ++j) {
            unsigned c = lh[t * CH + j];
            if (cum + c >= k) { res[0] = (unsigned)(NB - 1 - (t * CH + j)); res[1] = k - cum; break; }
            cum += c;
        }
    }
    __syncthreads();
}

__global__ void init_kernel(unsigned* __restrict__ hist0, unsigned* __restrict__ hist1,
                            unsigned* __restrict__ hist2, SelState* __restrict__ st,
                            unsigned force_fb) {
    int t = blockIdx.x * blockDim.x + threadIdx.x;
    int stride = gridDim.x * blockDim.x;
    for (int i = t; i < BINS12; i += stride) { hist0[i] = 0; hist1[i] = 0; }
    if (t < BINS8) hist2[t] = 0;
    if (t == 0) {
        st->forced_fb = force_fb;
        st->bufcount = 0;
        st->overflow = 0;
    }
}

// Fused: stream x once -> write out=0 everywhere, compact (key,idx) of candidates >= GUESS.
__global__ __launch_bounds__(256) void pass1_kernel(const float* __restrict__ x,
                                                    float* __restrict__ out, long long n,
                                                    unsigned* __restrict__ keys,
                                                    unsigned* __restrict__ idxs,
                                                    unsigned bufcap, SelState* __restrict__ st) {
    if (st->forced_fb) return;  // fallback path rewrites everything later
    __shared__ unsigned lkey[LCAP];
    __shared__ unsigned lidx[LCAP];
    __shared__ unsigned lcnt;
    __shared__ unsigned gbase;
    if (threadIdx.x == 0) lcnt = 0;
    __syncthreads();

    const unsigned GKEY = f2key(GUESS);
    long long n4 = n >> 2;
    long long tid = (long long)blockIdx.x * blockDim.x + threadIdx.x;
    long long stride = (long long)gridDim.x * blockDim.x;
    const f4v* xv = (const f4v*)x;
    f4v* ov = (f4v*)out;
    f4v z4 = {0.f, 0.f, 0.f, 0.f};

    for (long long i = tid; i < n4; i += stride) {
        f4v v = __builtin_nontemporal_load(&xv[i]);
        __builtin_nontemporal_store(z4, &ov[i]);
#pragma unroll
        for (int c = 0; c < 4; ++c) {
            unsigned key = f2key(v[c]);
            if (key >= GKEY) {
                unsigned p = atomicAdd(&lcnt, 1u);
                if (p < LCAP) { lkey[p] = key; lidx[p] = (unsigned)((i << 2) + c); }
            }
        }
    }
    for (long long i = (n4 << 2) + tid; i < n; i += stride) {
        float v = x[i];
        out[i] = 0.f;
        unsigned key = f2key(v);
        if (key >= GKEY) {
            unsigned p = atomicAdd(&lcnt, 1u);
            if (p < LCAP) { lkey[p] = key; lidx[p] = (unsigned)i; }
        }
    }

    __syncthreads();
    unsigned cnt = lcnt;
    if (cnt > LCAP) cnt = LCAP;
    if (threadIdx.x == 0) {
        if (lcnt > LCAP) atomicOr(&st->overflow, 1u);
        unsigned base = atomicAdd(&st->bufcount, cnt);
        if (base + cnt > bufcap) atomicOr(&st->overflow, 1u);
        gbase = base;
    }
    __syncthreads();
    unsigned base = gbase;
    for (unsigned i = threadIdx.x; i < cnt; i += 256) {
        unsigned dst = base + i;
        if (dst < bufcap) { keys[dst] = lkey[i]; idxs[dst] = lidx[i]; }
    }
}

// hist0: compact path over candidate keys; fallback over full x.
__global__ __launch_bounds__(256) void hist0_kernel(const float* __restrict__ x, long long n,
                                                    const unsigned* __restrict__ keys,
                                                    unsigned* __restrict__ hist0,
                                                    const SelState* __restrict__ st,
                                                    unsigned total_k) {
    __shared__ unsigned lh[BINS12];
    for (int i = threadIdx.x; i < BINS12; i += 256) lh[i] = 0;
    __syncthreads();

    long long tid = (long long)blockIdx.x * blockDim.x + threadIdx.x;
    long long stride = (long long)gridDim.x * blockDim.x;

    if (is_fb(st, total_k)) {
        long long n4 = n >> 2;
        const float4* x4 = (const float4*)x;
        for (long long i = tid; i < n4; i += stride) {
            float4 v = x4[i];
            float vv[4] = {v.x, v.y, v.z, v.w};
#pragma unroll
            for (int c = 0; c < 4; ++c) atomicAdd(&lh[f2key(vv[c]) >> 20], 1u);
        }
        for (long long i = (n4 << 2) + tid; i < n; i += stride)
            atomicAdd(&lh[f2key(x[i]) >> 20], 1u);
    } else {
        long long cnt = (long long)st->bufcount;
        long long c4 = cnt >> 2;
        const uint4* k4 = (const uint4*)keys;
        for (long long i = tid; i < c4; i += stride) {
            uint4 kv = k4[i];
            atomicAdd(&lh[kv.x >> 20], 1u);
            atomicAdd(&lh[kv.y >> 20], 1u);
            atomicAdd(&lh[kv.z >> 20], 1u);
            atomicAdd(&lh[kv.w >> 20], 1u);
        }
        for (long long i = (c4 << 2) + tid; i < cnt; i += stride)
            atomicAdd(&lh[keys[i] >> 20], 1u);
    }

    __syncthreads();
    for (int i = threadIdx.x; i < BINS12; i += 256) {
        unsigned c = lh[i];
        if (c) atomicAdd(&hist0[i], c);
    }
}

// scan0 (recomputed per block) + hist1 accumulation.
__global__ __launch_bounds__(256) void hist1_kernel(const float* __restrict__ x, long long n,
                                                    const unsigned* __restrict__ keys,
                                                    const unsigned* __restrict__ hist0,
                                                    unsigned* __restrict__ hist1,
                                                    SelState* __restrict__ st,
                                                    unsigned total_k) {
    __shared__ unsigned lh[BINS12];
    __shared__ unsigned res[2];
    scan_desc<BINS12>(hist0, total_k, lh, res);
    const unsigned sel0 = res[0];
    if (threadIdx.x == 0 && blockIdx.x == 0) { st->sel0 = sel0; st->k1 = res[1]; }

    for (int i = threadIdx.x; i < BINS12; i += 256) lh[i] = 0;
    __syncthreads();

    long long tid = (long long)blockIdx.x * blockDim.x + threadIdx.x;
    long long stride = (long long)gridDim.x * blockDim.x;

    if (is_fb(st, total_k)) {
        long long n4 = n >> 2;
        const float4* x4 = (const float4*)x;
        for (long long i = tid; i < n4; i += stride) {
            float4 v = x4[i];
            float vv[4] = {v.x, v.y, v.z, v.w};
#pragma unroll
            for (int c = 0; c < 4; ++c) {
                unsigned key = f2key(vv[c]);
                if ((key >> 20) == sel0) atomicAdd(&lh[(key >> 8) & 0xFFFu], 1u);
            }
        }
        for (long long i = (n4 << 2) + tid; i < n; i += stride) {
            unsigned key = f2key(x[i]);
            if ((key >> 20) == sel0) atomicAdd(&lh[(key >> 8) & 0xFFFu], 1u);
        }
    } else {
        long long cnt = (long long)st->bufcount;
        long long c4 = cnt >> 2;
        const uint4* k4 = (const uint4*)keys;
        for (long long i = tid; i < c4; i += stride) {
            uint4 kv = k4[i];
            unsigned kk[4] = {kv.x, kv.y, kv.z, kv.w};
#pragma unroll
            for (int c = 0; c < 4; ++c)
                if ((kk[c] >> 20) == sel0) atomicAdd(&lh[(kk[c] >> 8) & 0xFFFu], 1u);
        }
        for (long long i = (c4 << 2) + tid; i < cnt; i += stride) {
            unsigned key = keys[i];
            if ((key >> 20) == sel0) atomicAdd(&lh[(key >> 8) & 0xFFFu], 1u);
        }
    }

    __syncthreads();
    for (int i = threadIdx.x; i < BINS12; i += 256) {
        unsigned c = lh[i];
        if (c) atomicAdd(&hist1[i], c);
    }
}

// scan1 (per block, k from st->k1) + hist2 accumulation.
__global__ __launch_bounds__(256) void hist2_kernel(const float* __restrict__ x, long long n,
                                                    const unsigned* __restrict__ keys,
                                                    const unsigned* __restrict__ hist1,
                                                    unsigned* __restrict__ hist2,
                                                    SelState* __restrict__ st,
                                                    unsigned total_k) {
    __shared__ unsigned lh[BINS12];
    __shared__ unsigned res[2];
    scan_desc<BINS12>(hist1, st->k1, lh, res);
    const unsigned sel1 = (st->sel0 << 12) | res[0];  // top-24 bits
    if (threadIdx.x == 0 && blockIdx.x == 0) { st->sel1 = sel1; st->k2 = res[1]; }

    for (int i = threadIdx.x; i < BINS8; i += 256) lh[i] = 0;
    __syncthreads();

    long long tid = (long long)blockIdx.x * blockDim.x + threadIdx.x;
    long long stride = (long long)gridDim.x * blockDim.x;

    if (is_fb(st, total_k)) {
        long long n4 = n >> 2;
        const float4* x4 = (const float4*)x;
        for (long long i = tid; i < n4; i += stride) {
            float4 v = x4[i];
            float vv[4] = {v.x, v.y, v.z, v.w};
#pragma unroll
            for (int c = 0; c < 4; ++c) {
                unsigned key = f2key(vv[c]);
                if ((key >> 8) == sel1) atomicAdd(&lh[key & 0xFFu], 1u);
            }
        }
        for (long long i = (n4 << 2) + tid; i < n; i += stride) {
            unsigned key = f2key(x[i]);
            if ((key >> 8) == sel1) atomicAdd(&lh[key & 0xFFu], 1u);
        }
    } else {
        long long cnt = (long long)st->bufcount;
        long long c4 = cnt >> 2;
        const uint4* k4 = (const uint4*)keys;
        for (long long i = tid; i < c4; i += stride) {
            uint4 kv = k4[i];
            unsigned kk[4] = {kv.x, kv.y, kv.z, kv.w};
#pragma unroll
            for (int c = 0; c < 4; ++c)
                if ((kk[c] >> 8) == sel1) atomicAdd(&lh[kk[c] & 0xFFu], 1u);
        }
        for (long long i = (c4 << 2) + tid; i < cnt; i += stride) {
            unsigned key = keys[i];
            if ((key >> 8) == sel1) atomicAdd(&lh[key & 0xFFu], 1u);
        }
    }

    __syncthreads();
    for (int i = threadIdx.x; i < BINS8; i += 256) {
        unsigned c = lh[i];
        if (c) atomicAdd(&hist2[i], c);
    }
}

// scan2 (per block, k from st->k2) -> threshold; compact scatter or fallback full gate.
__global__ __launch_bounds__(256) void gate_kernel(const float* __restrict__ x,
                                                   float* __restrict__ out, long long n,
                                                   const unsigned* __restrict__ keys,
                                                   const unsigned* __restrict__ idxs,
                                                   const unsigned* __restrict__ hist2,
                                                   const SelState* __restrict__ st,
                                                   unsigned total_k) {
    __shared__ unsigned lh[BINS8];
    __shared__ unsigned res[2];
    scan_desc<BINS8>(hist2, st->k2, lh, res);
    const unsigned tkey = (st->sel1 << 8) | res[0];

    long long tid = (long long)blockIdx.x * blockDim.x + threadIdx.x;
    long long stride = (long long)gridDim.x * blockDim.x;

    if (is_fb(st, total_k)) {
        float thr = key2f(tkey);
        long long n4 = n >> 2;
        const float4* x4 = (const float4*)x;
        float4* o4 = (float4*)out;
        for (long long i = tid; i < n4; i += stride) {
            float4 v = x4[i];
            float4 r;
            r.x = (v.x >= thr) ? fmaxf(v.x, 0.f) : 0.f;
            r.y = (v.y >= thr) ? fmaxf(v.y, 0.f) : 0.f;
            r.z = (v.z >= thr) ? fmaxf(v.z, 0.f) : 0.f;
            r.w = (v.w >= thr) ? fmaxf(v.w, 0.f) : 0.f;
            o4[i] = r;
        }
        for (long long i = (n4 << 2) + tid; i < n; i += stride) {
            float v = x[i];
            out[i] = (v >= thr) ? fmaxf(v, 0.f) : 0.f;
        }
    } else {
        // All non-candidates already zeroed by pass1. thr >= GUESS > 0 so relu(x)=x here.
        long long cnt = (long long)st->bufcount;
        for (long long i = tid; i < cnt; i += stride) {
            unsigned kk = keys[i];
            if (kk >= tkey) out[idxs[i]] = key2f(kk);
        }
    }
}

}  // namespace

extern "C" void kernel_launch(void* const* d_in, const int* in_sizes, int n_in,
                              void* d_out, int out_size, void* d_ws, size_t ws_size,
                              hipStream_t stream) {
    const float* x = (const float*)d_in[0];
    float* out = (float*)d_out;
    long long n = (long long)in_sizes[0];

    long long tk = 64LL * 4096LL;
    if (tk > n) tk = n;
    unsigned total_k = (unsigned)tk;

    char* ws = (char*)d_ws;
    unsigned* hist0 = (unsigned*)(ws);            // 16 KiB
    unsigned* hist1 = (unsigned*)(ws + 16384);    // 16 KiB
    unsigned* hist2 = (unsigned*)(ws + 32768);    // 1 KiB
    SelState* st    = (SelState*)(ws + 33792);

    // Candidate arrays: keys then idxs, each bufcap entries (bufcap multiple of 4).
    unsigned bufcap = 0;
    unsigned* keys = (unsigned*)(ws + 65536);
    unsigned* idxs = nullptr;
    if (ws_size > 65536) {
        size_t avail = (ws_size - 65536) / 8;  // two u32 arrays
        size_t cap = avail > 16u * 1024u * 1024u ? 16u * 1024u * 1024u : avail;
        bufcap = (unsigned)(cap & ~3ull);
        idxs = keys + bufcap;
    }
    unsigned force_fb = (bufcap < 2u * total_k || n > 0xFFFF0000LL) ? 1u : 0u;

    const int blocks = 2048;

    init_kernel<<<16, 256, 0, stream>>>(hist0, hist1, hist2, st, force_fb);
    pass1_kernel<<<blocks, 256, 0, stream>>>(x, out, n, keys, idxs, bufcap, st);
    hist0_kernel<<<blocks, 256, 0, stream>>>(x, n, keys, hist0, st, total_k);
    hist1_kernel<<<blocks, 256, 0, stream>>>(x, n, keys, hist0, hist1, st, total_k);
    hist2_kernel<<<blocks, 256, 0, stream>>>(x, n, keys, hist1, hist2, st, total_k);
    gate_kernel<<<blocks, 256, 0, stream>>>(x, out, n, keys, idxs, hist2, st, total_k);
}